// Round 3
// baseline (371.503 us; speedup 1.0000x reference)
//
#include <hip/hip_runtime.h>
#include <stdint.h>

// ReverbAugment: reference is JAX cross-correlation with left-pad K-1:
//   y[t] = sum_j h[j]*x[t-j],  h[j] = rir[K-1-j]   (time-REVERSED rir!)
// then y /= (max|y| + 1e-8).
// Strategy: bf16 MFMA 32x32x16. D[m][n] = y[tw+32n+m] = sum_c h[d+m-c] * x[s0+32n+c]
//   A (h Toeplitz slabs) precomputed per-launch into d_ws in exact lane layout (L2-resident, 1MB)
//   B (x window) staged per-block into LDS (bf16, XOR-swizzled to kill bank conflicts)

#define T_LEN   160000
#define BATCH   32
#define K_LEN   16000
#define NCHUNK  1002            // d = 16*j - 16, j = 0..1001  (covers tap-index in [0,16000) for all m)
#define BLOCKS_PER_ROW 40
#define BLOCK_TILE 4096         // 4 waves x 1024 outputs
#define NST     (K_LEN + BLOCK_TILE)   // 20096 staged x elems per block
#define NST8    (NST / 8)
#define LY_PITCH 33             // +1 padded row for conflict-free D transpose

typedef __attribute__((ext_vector_type(8)))  short short8;
typedef __attribute__((ext_vector_type(16))) float f32x16;

// bijective XOR swizzle on LDS byte addresses (moves 16B slots within 128B blocks).
// B-read pattern byte = base + 64r + 16h is a 16-way conflict unswizzled; this makes it ~2-way (free).
__device__ __forceinline__ unsigned swz(unsigned b) {
  return b ^ (((b >> 7) & 7u) << 4);
}

__device__ __forceinline__ short f2bf(float f) {   // round-to-nearest-even f32 -> bf16
  unsigned u = __float_as_uint(f);
  u += 0x7fffu + ((u >> 16) & 1u);
  return (short)(u >> 16);
}

// Build A-operand table: atab[j*64 + lane] = 8 bf16,
// element e = h[d_j + (lane&31) - (8*(lane>>5)+e)], h[i] = rir[K-1-i]
// (A fragment layout for mfma_f32_32x32x16_bf16: row = lane&31, k = 8*(lane>>5)+e)
__global__ __launch_bounds__(256) void build_atab_k(
    const float* __restrict__ rir, short8* __restrict__ atab, unsigned* __restrict__ wsmax)
{
  int tid = blockIdx.x * 256 + threadIdx.x;
  if (tid == 0) *wsmax = 0u;                // ws is poisoned 0xAA each launch; init max here
  if (tid >= NCHUNK * 64) return;
  int j = tid >> 6, l = tid & 63;
  int m = l & 31, h = l >> 5;
  int d = 16 * j - 16;
  short8 o;
  #pragma unroll
  for (int e = 0; e < 8; ++e) {
    int k = d + m - (8 * h + e);            // tap index into h
    float v = (k >= 0 && k < K_LEN) ? rir[K_LEN - 1 - k] : 0.0f;   // h[k] = rir[K-1-k]
    o[e] = f2bf(v);
  }
  atab[tid] = o;
}

__global__ __launch_bounds__(256) void conv_k(
    const float* __restrict__ x, const short8* __restrict__ atab,
    float* __restrict__ out, unsigned* __restrict__ wsmax)
{
  __shared__ __align__(16) char smem[NST * 2];   // 40192 B: x stage (bf16), later reused for D transpose
  __shared__ float wmaxs[4];

  int blk = blockIdx.x;
  int b   = blk / BLOCKS_PER_ROW;
  int tb  = (blk - b * BLOCKS_PER_ROW) * BLOCK_TILE;
  const float* __restrict__ xrow = x + (size_t)b * T_LEN;
  int s_base = tb - K_LEN;                       // left edge of staged window (can be < 0)
  int tid = threadIdx.x;

  // ---- stage x[s_base .. s_base+NST) as bf16 into swizzled LDS ----
  for (int i = tid; i < NST8; i += 256) {
    int s = s_base + i * 8;
    float v[8];
    if (s >= 0 && s + 8 <= T_LEN) {
      float4 a0 = *(const float4*)(xrow + s);
      float4 a1 = *(const float4*)(xrow + s + 4);
      v[0]=a0.x; v[1]=a0.y; v[2]=a0.z; v[3]=a0.w;
      v[4]=a1.x; v[5]=a1.y; v[6]=a1.z; v[7]=a1.w;
    } else {
      #pragma unroll
      for (int e = 0; e < 8; ++e) {
        int se = s + e;
        v[e] = (se >= 0 && se < T_LEN) ? xrow[se] : 0.0f;
      }
    }
    short8 hv;
    #pragma unroll
    for (int e = 0; e < 8; ++e) hv[e] = f2bf(v[e]);
    *(short8*)(smem + swz((unsigned)(i * 16))) = hv;
  }
  __syncthreads();

  // ---- MFMA chunk loop ----
  int l  = tid & 63;
  int w  = tid >> 6;        // wave id: owns outputs [tb+1024w, tb+1024w+1024)
  int q  = l & 31;          // lane column
  int hh = l >> 5;

  f32x16 acc;
  #pragma unroll
  for (int r = 0; r < 16; ++r) acc[r] = 0.0f;

  const short8* ap = atab + l;
  // B fragment lane elem offset at j=0: (s0_j - s_base) + 32*(l&31) + 8*(l>>5); s0_j = tw + 16 - 16j
  int boff0 = (K_LEN + 16) + 1024 * w + 32 * q + 8 * hh;

  #pragma unroll 2
  for (int j = 0; j < NCHUNK; ++j) {
    short8 a = ap[j * 64];                                   // h Toeplitz fragment (L1/L2)
    unsigned byteoff = (unsigned)((boff0 - 16 * j) * 2);
    short8 bv = *(const short8*)(smem + swz(byteoff));       // x fragment from LDS
    acc = __builtin_amdgcn_mfma_f32_32x32x16_bf16(a, bv, acc, 0, 0, 0);
  }
  __syncthreads();   // everyone done with x stage; reuse smem as D transpose buffer

  // ---- transpose D through LDS (padded rows; write is 2-way conflict = free) ----
  // D layout: col n = lane&31, row m = (r&3) + 8*(r>>2) + 4*(lane>>5); t = tw + 32n + m
  float* ly = (float*)smem;                                  // [4][32][LY_PITCH] = 16896 B
  #pragma unroll
  for (int r = 0; r < 16; ++r) {
    int m = (r & 3) + 8 * (r >> 2) + 4 * hh;
    ly[(w * 32 + q) * LY_PITCH + m] = acc[r];
  }
  __syncthreads();

  // ---- coalesced store + block abs-max ----
  float lm = 0.0f;
  float* __restrict__ orow = out + (size_t)b * T_LEN + tb;
  for (int g = tid; g < BLOCK_TILE / 4; g += 256) {
    int t_loc = 4 * g;
    int t = tb + t_loc;
    if (t < T_LEN) {
      int wv  = t_loc >> 10;
      int rem = t_loc & 1023;
      int qq  = rem >> 5;
      int m0  = rem & 31;                 // multiple of 4
      int phys = (wv * 32 + qq) * LY_PITCH + m0;
      float4 o4;
      o4.x = ly[phys + 0]; o4.y = ly[phys + 1]; o4.z = ly[phys + 2]; o4.w = ly[phys + 3];
      *(float4*)(orow + t_loc) = o4;
      lm = fmaxf(lm, fmaxf(fmaxf(fabsf(o4.x), fabsf(o4.y)), fmaxf(fabsf(o4.z), fabsf(o4.w))));
    }
  }
  #pragma unroll
  for (int off = 32; off; off >>= 1) lm = fmaxf(lm, __shfl_xor(lm, off));
  if (l == 0) wmaxs[w] = lm;
  __syncthreads();
  if (tid == 0) {
    float m4 = fmaxf(fmaxf(wmaxs[0], wmaxs[1]), fmaxf(wmaxs[2], wmaxs[3]));
    atomicMax(wsmax, __float_as_uint(m4));   // |y| >= 0: uint order == float order
  }
}

__global__ __launch_bounds__(256) void normalize_k(
    float* __restrict__ out, const unsigned* __restrict__ wsmax, int n4)
{
  float mx = __uint_as_float(*wsmax);
  float s = 1.0f / (mx + 1e-8f);
  int stride = gridDim.x * blockDim.x;
  for (int i = blockIdx.x * blockDim.x + threadIdx.x; i < n4; i += stride) {
    float4 v = ((const float4*)out)[i];
    v.x *= s; v.y *= s; v.z *= s; v.w *= s;
    ((float4*)out)[i] = v;
  }
}

extern "C" void kernel_launch(void* const* d_in, const int* in_sizes, int n_in,
                              void* d_out, int out_size, void* d_ws, size_t ws_size,
                              hipStream_t stream) {
  const float* wav = (const float*)d_in[0];
  const float* rir = (const float*)d_in[1];
  float* outp      = (float*)d_out;
  unsigned* wsmax  = (unsigned*)d_ws;
  short8* atab     = (short8*)((char*)d_ws + 256);   // 1,026,048 B table

  hipLaunchKernelGGL(build_atab_k, dim3((NCHUNK * 64 + 255) / 256), dim3(256), 0, stream,
                     rir, atab, wsmax);
  hipLaunchKernelGGL(conv_k, dim3(BATCH * BLOCKS_PER_ROW), dim3(256), 0, stream,
                     wav, atab, outp, wsmax);
  hipLaunchKernelGGL(normalize_k, dim3(1280), dim3(256), 0, stream,
                     outp, wsmax, (BATCH * T_LEN) / 4);
}

// Round 6
// 243.650 us; speedup vs baseline: 1.5247x; 1.5247x over previous
//
#include <hip/hip_runtime.h>
#include <stdint.h>

// ReverbAugment: y[t] = sum_j h[j]*x[t-j], h[j] = rir[K-1-j] (JAX cross-correlation), then /= max|y|+1e-8.
// bf16 MFMA 32x32x16, A = h-Toeplitz table (vmem, L1/L2-shared), B = x window (LDS, swizzled).
// R4: 4 independent acc chains/wave (2 tiles x 2 K-parities) + prefetch; 640 blocks x 4 waves.

#define T_LEN   160000
#define BATCH   32
#define K_LEN   16000
#define NCHUNK  1002
#define NCHUNK_PAD 1004          // +2 zero chunks so prefetch overruns are in-bounds
#define BPR     20               // blocks per row
#define BLK_OUT 8192             // outputs per block (4 waves x 2 tiles x 1024)
#define NST     (K_LEN + BLK_OUT)   // 24192 staged x elems
#define NST8    (NST / 8)
#define LY_PITCH 33

typedef __attribute__((ext_vector_type(8)))  short short8;
typedef __attribute__((ext_vector_type(16))) float f32x16;

__device__ __forceinline__ unsigned swz(unsigned b) {   // involution: spreads 16B slots across bank groups
  return b ^ (((b >> 7) & 7u) << 4);
}

__device__ __forceinline__ short f2bf(float f) {
  unsigned u = __float_as_uint(f);
  u += 0x7fffu + ((u >> 16) & 1u);
  return (short)(u >> 16);
}

// A table: atab[j*64 + lane] elem e = h[16j-16 + (lane&31) - (8*(lane>>5)+e)], h[i]=rir[K-1-i].
// j in [0,1004): j>=1002 gives all taps >= K_LEN -> zeros (prefetch pad).
__global__ __launch_bounds__(256) void build_atab_k(
    const float* __restrict__ rir, short8* __restrict__ atab, unsigned* __restrict__ wsmax)
{
  int tid = blockIdx.x * 256 + threadIdx.x;
  if (tid == 0) *wsmax = 0u;
  if (tid >= NCHUNK_PAD * 64) return;
  int j = tid >> 6, l = tid & 63;
  int m = l & 31, h = l >> 5;
  int d = 16 * j - 16;
  short8 o;
  #pragma unroll
  for (int e = 0; e < 8; ++e) {
    int k = d + m - (8 * h + e);
    float v = (k >= 0 && k < K_LEN) ? rir[K_LEN - 1 - k] : 0.0f;
    o[e] = f2bf(v);
  }
  atab[tid] = o;
}

__device__ __forceinline__ short8 lds_rd(const char* smem, int elem) {
  int byte = elem * 2;
  byte = byte < 0 ? 0 : byte;          // clamp for tail prefetch (result discarded)
  return *(const short8*)(smem + swz((unsigned)byte));
}

__global__ __launch_bounds__(256, 3) void conv_k(
    const float* __restrict__ x, const short8* __restrict__ atab,
    float* __restrict__ out, unsigned* __restrict__ wsmax)
{
  __shared__ __align__(16) char smem[NST * 2];   // 48384 B -> 3 blocks/CU
  __shared__ float wmaxs[4];

  int blk  = blockIdx.x;
  int brow = blk / BPR;
  int tb   = (blk - brow * BPR) * BLK_OUT;
  const float* __restrict__ xrow = x + (size_t)brow * T_LEN;
  int s_base = tb - K_LEN;
  int tid = threadIdx.x;

  // ---- stage x[s_base .. s_base+NST) as bf16 into swizzled LDS ----
  for (int i = tid; i < NST8; i += 256) {
    int s = s_base + i * 8;
    float v[8];
    if (s >= 0 && s + 8 <= T_LEN) {
      float4 a0 = *(const float4*)(xrow + s);
      float4 a1 = *(const float4*)(xrow + s + 4);
      v[0]=a0.x; v[1]=a0.y; v[2]=a0.z; v[3]=a0.w;
      v[4]=a1.x; v[5]=a1.y; v[6]=a1.z; v[7]=a1.w;
    } else {
      #pragma unroll
      for (int e = 0; e < 8; ++e) {
        int se = s + e;
        v[e] = (se >= 0 && se < T_LEN) ? xrow[se] : 0.0f;
      }
    }
    short8 hv;
    #pragma unroll
    for (int e = 0; e < 8; ++e) hv[e] = f2bf(v[e]);
    *(short8*)(smem + swz((unsigned)(i * 16))) = hv;
  }
  __syncthreads();

  // ---- MFMA loop: wave w owns tiles at tb+2048w and tb+2048w+1024 ----
  int l  = tid & 63;
  int w  = tid >> 6;
  int q  = l & 31;
  int hh = l >> 5;

  f32x16 acc00, acc01, acc10, acc11;   // [parity][tile]
  #pragma unroll
  for (int r = 0; r < 16; ++r) { acc00[r]=0.f; acc01[r]=0.f; acc10[r]=0.f; acc11[r]=0.f; }

  const short8* ap = atab + l;
  // staged elem offset for (tile b, chunk s): base0 + 1024b - 16s
  int base0 = (K_LEN + 16) + 2048 * w + 32 * q + 8 * hh;

  short8 a0 = ap[0];
  short8 a1 = ap[64];
  short8 b00 = lds_rd(smem, base0);
  short8 b01 = lds_rd(smem, base0 + 1024);
  short8 b10 = lds_rd(smem, base0 - 16);
  short8 b11 = lds_rd(smem, base0 + 1024 - 16);

  for (int s = 0; s < NCHUNK; s += 2) {
    // prefetch pair s+2, s+3 (tail reads hit zero-padded atab / clamped LDS; values unused)
    short8 a0n = ap[(s + 2) * 64];
    short8 a1n = ap[(s + 3) * 64];
    int e2 = base0 - 16 * (s + 2);
    short8 b00n = lds_rd(smem, e2);
    short8 b01n = lds_rd(smem, e2 + 1024);
    short8 b10n = lds_rd(smem, e2 - 16);
    short8 b11n = lds_rd(smem, e2 + 1024 - 16);

    acc00 = __builtin_amdgcn_mfma_f32_32x32x16_bf16(a0, b00, acc00, 0, 0, 0);
    acc01 = __builtin_amdgcn_mfma_f32_32x32x16_bf16(a0, b01, acc01, 0, 0, 0);
    acc10 = __builtin_amdgcn_mfma_f32_32x32x16_bf16(a1, b10, acc10, 0, 0, 0);
    acc11 = __builtin_amdgcn_mfma_f32_32x32x16_bf16(a1, b11, acc11, 0, 0, 0);

    a0 = a0n; a1 = a1n; b00 = b00n; b01 = b01n; b10 = b10n; b11 = b11n;
  }
  __syncthreads();   // all waves done with x stage; reuse smem for D transpose

  // ---- per-wave transpose + store + max (2 tiles) ----
  float* ly = (float*)smem + w * (32 * LY_PITCH);   // 4224 B per wave
  float lm = 0.0f;
  const float* __restrict__ orow_c = out + (size_t)brow * T_LEN;
  float* __restrict__ orow = (float*)orow_c;

  #pragma unroll
  for (int b = 0; b < 2; ++b) {
    f32x16 v;
    #pragma unroll
    for (int r = 0; r < 16; ++r)
      v[r] = (b == 0 ? acc00[r] + acc10[r] : acc01[r] + acc11[r]);
    #pragma unroll
    for (int r = 0; r < 16; ++r) {
      int m = (r & 3) + 8 * (r >> 2) + 4 * hh;   // D row
      ly[q * LY_PITCH + m] = v[r];               // q = D col
    }
    int tbase = tb + 2048 * w + 1024 * b;
    #pragma unroll
    for (int p = 0; p < 4; ++p) {
      int t_loc = 256 * p + 4 * l;
      int t = tbase + t_loc;
      if (t < T_LEN) {
        int phys = (t_loc >> 5) * LY_PITCH + (t_loc & 31);
        float4 o4;
        o4.x = ly[phys + 0]; o4.y = ly[phys + 1]; o4.z = ly[phys + 2]; o4.w = ly[phys + 3];
        *(float4*)(orow + t) = o4;
        lm = fmaxf(lm, fmaxf(fmaxf(fabsf(o4.x), fabsf(o4.y)), fmaxf(fabsf(o4.z), fabsf(o4.w))));
      }
    }
  }

  #pragma unroll
  for (int off = 32; off; off >>= 1) lm = fmaxf(lm, __shfl_xor(lm, off));
  if (l == 0) wmaxs[w] = lm;
  __syncthreads();
  if (tid == 0) {
    float m4 = fmaxf(fmaxf(wmaxs[0], wmaxs[1]), fmaxf(wmaxs[2], wmaxs[3]));
    atomicMax(wsmax, __float_as_uint(m4));
  }
}

__global__ __launch_bounds__(256) void normalize_k(
    float* __restrict__ out, const unsigned* __restrict__ wsmax, int n4)
{
  float mx = __uint_as_float(*wsmax);
  float s = 1.0f / (mx + 1e-8f);
  int stride = gridDim.x * blockDim.x;
  for (int i = blockIdx.x * blockDim.x + threadIdx.x; i < n4; i += stride) {
    float4 v = ((const float4*)out)[i];
    v.x *= s; v.y *= s; v.z *= s; v.w *= s;
    ((float4*)out)[i] = v;
  }
}

extern "C" void kernel_launch(void* const* d_in, const int* in_sizes, int n_in,
                              void* d_out, int out_size, void* d_ws, size_t ws_size,
                              hipStream_t stream) {
  const float* wav = (const float*)d_in[0];
  const float* rir = (const float*)d_in[1];
  float* outp      = (float*)d_out;
  unsigned* wsmax  = (unsigned*)d_ws;
  short8* atab     = (short8*)((char*)d_ws + 256);   // 1,028,096 B

  hipLaunchKernelGGL(build_atab_k, dim3((NCHUNK_PAD * 64 + 255) / 256), dim3(256), 0, stream,
                     rir, atab, wsmax);
  hipLaunchKernelGGL(conv_k, dim3(BATCH * BPR), dim3(256), 0, stream,
                     wav, atab, outp, wsmax);
  hipLaunchKernelGGL(normalize_k, dim3(1280), dim3(256), 0, stream,
                     outp, wsmax, (BATCH * T_LEN) / 4);
}